// Round 13
// baseline (421.136 us; speedup 1.0000x reference)
//
#include <hip/hip_runtime.h>
#include <hip/hip_bf16.h>

#define N_NODES 50000
#define N_EDGES 800000
#define DIM 128

typedef __attribute__((ext_vector_type(8))) short bf16x8;
typedef __attribute__((ext_vector_type(4))) float f32x4;

static __device__ __forceinline__ unsigned short f2bf(float f) {
    unsigned int u = __float_as_uint(f);
    u += 0x7fffu + ((u >> 16) & 1u);  // round-to-nearest-even
    return (unsigned short)(u >> 16);
}
static __device__ __forceinline__ float bflo(unsigned int u) {
    return __uint_as_float(u << 16);
}
static __device__ __forceinline__ float bfhi(unsigned int u) {
    return __uint_as_float(u & 0xffff0000u);
}

// ---------------------------------------------------------------------------
// fp32 -> bf16 bulk convert (pre-pass; rounding identical to GEMM staging)
// ---------------------------------------------------------------------------
__global__ __launch_bounds__(256) void cvt_f32_bf16(
    const float* __restrict__ in, unsigned short* __restrict__ out, int n)
{
    int i = (blockIdx.x * 256 + threadIdx.x) * 4;
    if (i + 3 < n) {
        const float4 t = *(const float4*)&in[i];
        union { unsigned short us[4]; uint2 v; } o;
        o.us[0] = f2bf(t.x); o.us[1] = f2bf(t.y);
        o.us[2] = f2bf(t.z); o.us[3] = f2bf(t.w);
        *(uint2*)&out[i] = o.v;
    } else {
        for (; i < n; i++) out[i] = f2bf(in[i]);
    }
}

// ---------------------------------------------------------------------------
// Edge binning: histogram -> parallel exclusive scan -> bin scatter.
// hist/bin process 4 edges per thread for memory-level parallelism.
// ---------------------------------------------------------------------------
__global__ __launch_bounds__(256) void hist_dst(
    const int* __restrict__ dst, int* __restrict__ bins, int E)
{
    const int e = (blockIdx.x * 256 + threadIdx.x) * 4;
    if (e + 3 < E) {
        const int4 d = *(const int4*)&dst[e];
        atomicAdd(&bins[d.x], 1);
        atomicAdd(&bins[d.y], 1);
        atomicAdd(&bins[d.z], 1);
        atomicAdd(&bins[d.w], 1);
    } else {
        for (int i = e; i < E; i++) atomicAdd(&bins[dst[i]], 1);
    }
}

__global__ __launch_bounds__(256) void scan_blocks(
    int* __restrict__ data, int* __restrict__ bsums, int n)
{
    __shared__ int ws[4];
    const int tid = threadIdx.x, lane = tid & 63, wid = tid >> 6;
    const int i = blockIdx.x * 256 + tid;
    const int x = (i < n) ? data[i] : 0;
    int v = x;
    #pragma unroll
    for (int off = 1; off < 64; off <<= 1) {
        const int t = __shfl_up(v, off);
        if (lane >= off) v += t;
    }
    if (lane == 63) ws[wid] = v;
    __syncthreads();
    const int w0 = ws[0], w1 = ws[1], w2 = ws[2];
    const int woff = (wid > 0 ? w0 : 0) + (wid > 1 ? w1 : 0) + (wid > 2 ? w2 : 0);
    const int incl = v + woff;
    if (i < n) data[i] = incl - x;
    if (tid == 255) bsums[blockIdx.x] = incl;
}

__global__ __launch_bounds__(256) void scan_bsums(int* __restrict__ bsums, int nb)
{
    __shared__ int ws[4];
    const int tid = threadIdx.x, lane = tid & 63, wid = tid >> 6;
    const int x = (tid < nb) ? bsums[tid] : 0;
    int v = x;
    #pragma unroll
    for (int off = 1; off < 64; off <<= 1) {
        const int t = __shfl_up(v, off);
        if (lane >= off) v += t;
    }
    if (lane == 63) ws[wid] = v;
    __syncthreads();
    const int w0 = ws[0], w1 = ws[1], w2 = ws[2];
    const int woff = (wid > 0 ? w0 : 0) + (wid > 1 ? w1 : 0) + (wid > 2 ? w2 : 0);
    if (tid < nb) bsums[tid] = (v + woff) - x;
}

__global__ __launch_bounds__(256) void scan_add(
    int* __restrict__ data, const int* __restrict__ bsums, int n)
{
    const int i = blockIdx.x * 256 + threadIdx.x;
    if (i < n) data[i] += bsums[blockIdx.x];
}

__global__ __launch_bounds__(256) void bin_edges(
    const int* __restrict__ src, const int* __restrict__ dst,
    const float* __restrict__ ew, int* __restrict__ bins,
    int2* __restrict__ binned, int E)
{
    const int e = (blockIdx.x * 256 + threadIdx.x) * 4;
    if (e + 3 < E) {
        const int4   d = *(const int4*)&dst[e];
        const int4   s = *(const int4*)&src[e];
        const float4 w = *(const float4*)&ew[e];
        const int p0 = atomicAdd(&bins[d.x], 1);
        const int p1 = atomicAdd(&bins[d.y], 1);
        const int p2 = atomicAdd(&bins[d.z], 1);
        const int p3 = atomicAdd(&bins[d.w], 1);
        binned[p0] = make_int2(s.x, __float_as_int(w.x));
        binned[p1] = make_int2(s.y, __float_as_int(w.y));
        binned[p2] = make_int2(s.z, __float_as_int(w.z));
        binned[p3] = make_int2(s.w, __float_as_int(w.w));
    } else {
        for (int i = e; i < E; i++) {
            const int pos = atomicAdd(&bins[dst[i]], 1);
            binned[pos] = make_int2(src[i], __float_as_int(ew[i]));
        }
    }
}

// ---------------------------------------------------------------------------
// Gather-reduce over bf16 n: one wave per dst; lane covers feats {2l, 2l+1}.
// 8-edge unroll. Writes agg as bf16, pre-divided by clamp(sum_w, 1).
// ---------------------------------------------------------------------------
__global__ __launch_bounds__(256) void gather_agg(
    const unsigned short* __restrict__ nsrc, const int2* __restrict__ binned,
    const int* __restrict__ bins, unsigned short* __restrict__ agg, int N)
{
    const int lane = threadIdx.x & 63;
    const int d    = blockIdx.x * 4 + (threadIdx.x >> 6);
    if (d >= N) return;
    const int lo = (d == 0) ? 0 : bins[d - 1];
    const int hi = bins[d];
    float accx = 0.f, accy = 0.f, ws = 0.f;
    int p = lo;
    for (; p + 7 < hi; p += 8) {
        int2 s[8];
        unsigned int u[8];
        #pragma unroll
        for (int i = 0; i < 8; i++) s[i] = binned[p + i];
        #pragma unroll
        for (int i = 0; i < 8; i++)
            u[i] = *(const unsigned int*)&nsrc[(size_t)s[i].x * DIM + lane * 2];
        #pragma unroll
        for (int i = 0; i < 8; i++) {
            const float w = __int_as_float(s[i].y);
            accx = fmaf(bflo(u[i]), w, accx);
            accy = fmaf(bfhi(u[i]), w, accy);
            ws += w;
        }
    }
    for (; p < hi; ++p) {
        const int2 sw = binned[p];
        const float w = __int_as_float(sw.y);
        const unsigned int u = *(const unsigned int*)&nsrc[(size_t)sw.x * DIM + lane * 2];
        accx = fmaf(bflo(u), w, accx); accy = fmaf(bfhi(u), w, accy);
        ws += w;
    }
    const float inv = 1.f / fmaxf(ws, 1.f);
    const unsigned int o = ((unsigned int)f2bf(accy * inv) << 16) | f2bf(accx * inv);
    *(unsigned int*)&agg[(size_t)d * DIM + lane * 2] = o;
}

// ---------------------------------------------------------------------------
// MFMA GEMM machinery: 128x128 tile, 4 waves; wave wv owns rows [wv*32,+32).
// All operands bf16 in memory -> staging is pure uint4 copies into swizzled
// LDS: elem (row,k) at [row][(g^(row&7))*8 + k%8], g=k>>3. 0 bank conflicts.
// A/B frag: row|col = lane&15, k = (lane>>4)*8+i. C/D: col=lane&15,
// row=(lane>>4)*4+reg (HW-verified).
// ---------------------------------------------------------------------------

// GEMM1: n = relu(A @ Q^T + qb) -> bf16. K = 128.
__global__ __launch_bounds__(256) void qgemm_relu(
    const unsigned short* __restrict__ A, const unsigned short* __restrict__ Q,
    const float* __restrict__ qb, unsigned short* __restrict__ out, int N)
{
    __shared__ unsigned short Al[128][128];
    __shared__ unsigned short Bl[128][128];
    const int tid = threadIdx.x;
    const int lane = tid & 63, wv = tid >> 6;
    const int lc = lane & 15, lk = lane >> 4;
    const int r0 = blockIdx.x * 128;

    for (int id = tid; id < 2048; id += 256) {
        const int row = id >> 4, g = id & 15;
        const int gs = (g ^ (row & 7)) * 8;
        *(uint4*)&Al[row][gs] = *(const uint4*)&A[(size_t)(r0 + row) * DIM + g * 8];
        *(uint4*)&Bl[row][gs] = *(const uint4*)&Q[(size_t)row * DIM + g * 8];
    }
    __syncthreads();

    f32x4 acc[2][8];
    #pragma unroll
    for (int rf = 0; rf < 2; rf++)
        #pragma unroll
        for (int cf = 0; cf < 8; cf++)
            acc[rf][cf] = (f32x4){0.f, 0.f, 0.f, 0.f};

    #pragma unroll
    for (int ks = 0; ks < 4; ks++) {
        bf16x8 af[2], bfr[8];
        #pragma unroll
        for (int rf = 0; rf < 2; rf++) {
            const int row = wv * 32 + rf * 16 + lc;
            af[rf] = *(const bf16x8*)&Al[row][((ks * 4 + lk) ^ (row & 7)) * 8];
        }
        #pragma unroll
        for (int cf = 0; cf < 8; cf++) {
            const int col = cf * 16 + lc;
            bfr[cf] = *(const bf16x8*)&Bl[col][((ks * 4 + lk) ^ (col & 7)) * 8];
        }
        #pragma unroll
        for (int rf = 0; rf < 2; rf++)
            #pragma unroll
            for (int cf = 0; cf < 8; cf++)
                acc[rf][cf] = __builtin_amdgcn_mfma_f32_16x16x32_bf16(
                    af[rf], bfr[cf], acc[rf][cf], 0, 0, 0);
    }

    float bias[8];
    #pragma unroll
    for (int cf = 0; cf < 8; cf++) bias[cf] = qb[cf * 16 + lc];
    #pragma unroll
    for (int rf = 0; rf < 2; rf++)
        #pragma unroll
        for (int reg = 0; reg < 4; reg++) {
            const int r = r0 + wv * 32 + rf * 16 + lk * 4 + reg;
            if (r >= N) continue;
            #pragma unroll
            for (int cf = 0; cf < 8; cf++)
                out[(size_t)r * DIM + cf * 16 + lc] =
                    f2bf(fmaxf(acc[rf][cf][reg] + bias[cf], 0.f));
        }
}

// GEMM2 + epilogue: z = relu([agg, h] @ W^T + wb); h_next = z/||z||.
// write_out==0: write bf16 into hbuf IN PLACE (each block reads exactly its
// own row range before writing it). write_out==1: write fp32 to out.
__global__ __launch_bounds__(256) void wgemm_norm(
    const unsigned short* __restrict__ agg, unsigned short* __restrict__ hbuf,
    const unsigned short* __restrict__ W, const float* __restrict__ wb,
    float* __restrict__ out, int N, int write_out)
{
    __shared__ unsigned short Al[128][128];
    __shared__ unsigned short Bl[128][128];
    const int tid = threadIdx.x;
    const int lane = tid & 63, wv = tid >> 6;
    const int lc = lane & 15, lk = lane >> 4;
    const int r0 = blockIdx.x * 128;

    f32x4 acc[2][8];
    #pragma unroll
    for (int rf = 0; rf < 2; rf++)
        #pragma unroll
        for (int cf = 0; cf < 8; cf++)
            acc[rf][cf] = (f32x4){0.f, 0.f, 0.f, 0.f};

    for (int part = 0; part < 2; part++) {
        const unsigned short* __restrict__ Ap = part ? hbuf : agg;
        if (part) __syncthreads();  // previous part's LDS reads done
        for (int id = tid; id < 2048; id += 256) {
            const int row = id >> 4, g = id & 15;
            const int gs = (g ^ (row & 7)) * 8;
            *(uint4*)&Al[row][gs] = *(const uint4*)&Ap[(size_t)(r0 + row) * DIM + g * 8];
            *(uint4*)&Bl[row][gs] = *(const uint4*)&W[(size_t)row * 256 + part * 128 + g * 8];
        }
        __syncthreads();

        #pragma unroll
        for (int ks = 0; ks < 4; ks++) {
            bf16x8 af[2], bfr[8];
            #pragma unroll
            for (int rf = 0; rf < 2; rf++) {
                const int row = wv * 32 + rf * 16 + lc;
                af[rf] = *(const bf16x8*)&Al[row][((ks * 4 + lk) ^ (row & 7)) * 8];
            }
            #pragma unroll
            for (int cf = 0; cf < 8; cf++) {
                const int col = cf * 16 + lc;
                bfr[cf] = *(const bf16x8*)&Bl[col][((ks * 4 + lk) ^ (col & 7)) * 8];
            }
            #pragma unroll
            for (int rf = 0; rf < 2; rf++)
                #pragma unroll
                for (int cf = 0; cf < 8; cf++)
                    acc[rf][cf] = __builtin_amdgcn_mfma_f32_16x16x32_bf16(
                        af[rf], bfr[cf], acc[rf][cf], 0, 0, 0);
        }
    }

    float bias[8];
    #pragma unroll
    for (int cf = 0; cf < 8; cf++) bias[cf] = wb[cf * 16 + lc];
    #pragma unroll
    for (int rf = 0; rf < 2; rf++)
        #pragma unroll
        for (int reg = 0; reg < 4; reg++) {
            const int r = r0 + wv * 32 + rf * 16 + lk * 4 + reg;
            float z[8];
            float ss = 0.f;
            #pragma unroll
            for (int cf = 0; cf < 8; cf++) {
                z[cf] = fmaxf(acc[rf][cf][reg] + bias[cf], 0.f);
                ss = fmaf(z[cf], z[cf], ss);
            }
            #pragma unroll
            for (int m = 1; m < 16; m <<= 1) ss += __shfl_xor(ss, m);
            float zn = sqrtf(ss);
            if (zn == 0.f) zn = 1.f;
            const float rn = 1.f / zn;
            if (r < N) {
                if (write_out) {
                    #pragma unroll
                    for (int cf = 0; cf < 8; cf++)
                        out[(size_t)r * DIM + cf * 16 + lc] = z[cf] * rn;
                } else {
                    #pragma unroll
                    for (int cf = 0; cf < 8; cf++)
                        hbuf[(size_t)r * DIM + cf * 16 + lc] = f2bf(z[cf] * rn);
                }
            }
        }
}

extern "C" void kernel_launch(void* const* d_in, const int* in_sizes, int n_in,
                              void* d_out, int out_size, void* d_ws, size_t ws_size,
                              hipStream_t stream) {
    const float* h0  = (const float*)d_in[0];
    const float* ew  = (const float*)d_in[1];
    const float* Qw  = (const float*)d_in[2];
    const float* Qb  = (const float*)d_in[3];
    const float* Ww  = (const float*)d_in[4];
    const float* Wb  = (const float*)d_in[5];
    const int*  esrc = (const int*)d_in[6];
    const int*  edst = (const int*)d_in[7];
    float* out = (float*)d_out;

    unsigned short* hbuf = (unsigned short*)d_ws;            // 6.4M elems
    unsigned short* nbuf = hbuf + (size_t)N_NODES * DIM;     // 6.4M
    unsigned short* aggb = nbuf + (size_t)N_NODES * DIM;     // 6.4M
    unsigned short* qwb  = aggb + (size_t)N_NODES * DIM;     // 32768
    unsigned short* wwb  = qwb + 2 * DIM * DIM;              // 65536
    int*   bins   = (int*)(wwb + 2 * DIM * 2 * DIM);
    int2*  binned = (int2*)(bins + N_NODES);
    int*   bsums  = (int*)(binned + N_EDGES);

    const int gemm_blocks = (N_NODES + 127) / 128;   // 391
    const int e4_blocks   = (N_EDGES / 4 + 255) / 256;  // 782
    const int gath_blocks = (N_NODES + 3) / 4;
    const int scan_blocks_n = (N_NODES + 255) / 256; // 196

    // pre-pass: bf16-ize h0 and weights (rounding identical to old staging)
    cvt_f32_bf16<<<(N_NODES * DIM) / 1024, 256, 0, stream>>>(h0, hbuf, N_NODES * DIM);
    cvt_f32_bf16<<<(2 * DIM * DIM) / 1024, 256, 0, stream>>>(Qw, qwb, 2 * DIM * DIM);
    cvt_f32_bf16<<<(2 * DIM * 2 * DIM) / 1024, 256, 0, stream>>>(Ww, wwb, 2 * DIM * 2 * DIM);

    for (int l = 0; l < 2; l++) {
        const int*   src = esrc + (size_t)l * N_EDGES;
        const int*   dst = edst + (size_t)l * N_EDGES;
        const float* w   = ew + (size_t)l * N_EDGES;

        hipMemsetAsync(bins, 0, N_NODES * sizeof(int), stream);
        hist_dst<<<e4_blocks, 256, 0, stream>>>(dst, bins, N_EDGES);
        scan_blocks<<<scan_blocks_n, 256, 0, stream>>>(bins, bsums, N_NODES);
        scan_bsums<<<1, 256, 0, stream>>>(bsums, scan_blocks_n);
        scan_add<<<scan_blocks_n, 256, 0, stream>>>(bins, bsums, N_NODES);
        bin_edges<<<e4_blocks, 256, 0, stream>>>(src, dst, w, bins, binned, N_EDGES);
        qgemm_relu<<<gemm_blocks, 256, 0, stream>>>(
            hbuf, qwb + (size_t)l * DIM * DIM, Qb + (size_t)l * DIM, nbuf, N_NODES);
        gather_agg<<<gath_blocks, 256, 0, stream>>>(nbuf, binned, bins, aggb, N_NODES);
        wgemm_norm<<<gemm_blocks, 256, 0, stream>>>(
            aggb, hbuf, wwb + (size_t)l * DIM * 2 * DIM, Wb + (size_t)l * DIM,
            out, N_NODES, l == 1 ? 1 : 0);
    }
}

// Round 14
// 348.564 us; speedup vs baseline: 1.2082x; 1.2082x over previous
//
#include <hip/hip_runtime.h>
#include <hip/hip_bf16.h>

#define N_NODES 50000
#define N_EDGES 800000
#define DIM 128

typedef __attribute__((ext_vector_type(8))) short bf16x8;
typedef __attribute__((ext_vector_type(4))) float f32x4;

static __device__ __forceinline__ unsigned short f2bf(float f) {
    unsigned int u = __float_as_uint(f);
    u += 0x7fffu + ((u >> 16) & 1u);  // round-to-nearest-even
    return (unsigned short)(u >> 16);
}
static __device__ __forceinline__ float bflo(unsigned int u) {
    return __uint_as_float(u << 16);
}
static __device__ __forceinline__ float bfhi(unsigned int u) {
    return __uint_as_float(u & 0xffff0000u);
}

// ---------------------------------------------------------------------------
// fp32 -> bf16 bulk convert (pre-pass; rounding identical to GEMM staging)
// ---------------------------------------------------------------------------
__global__ __launch_bounds__(256) void cvt_f32_bf16(
    const float* __restrict__ in, unsigned short* __restrict__ out, int n)
{
    int i = (blockIdx.x * 256 + threadIdx.x) * 4;
    if (i + 3 < n) {
        const float4 t = *(const float4*)&in[i];
        union { unsigned short us[4]; uint2 v; } o;
        o.us[0] = f2bf(t.x); o.us[1] = f2bf(t.y);
        o.us[2] = f2bf(t.z); o.us[3] = f2bf(t.w);
        *(uint2*)&out[i] = o.v;
    } else {
        for (; i < n; i++) out[i] = f2bf(in[i]);
    }
}

// ---------------------------------------------------------------------------
// Edge binning, atomic-paid-once version:
//   hist_rank: counts[d]++ via atomic, SAVING the return as rank[e]
//   scan: exclusive starts[] from counts (counts preserved)
//   bin_place: binned[starts[dst]+rank] = (src,w)  -- NO atomic
// 1 edge/thread everywhere: latency-bound scatter needs max waves (R13 lesson).
// ---------------------------------------------------------------------------
__global__ __launch_bounds__(256) void hist_rank(
    const int* __restrict__ dst, int* __restrict__ counts,
    int* __restrict__ rank, int E)
{
    const int e = blockIdx.x * 256 + threadIdx.x;
    if (e < E) rank[e] = atomicAdd(&counts[dst[e]], 1);
}

__global__ __launch_bounds__(256) void scan_blocks(
    const int* __restrict__ cnt, int* __restrict__ starts,
    int* __restrict__ bsums, int n)
{
    __shared__ int ws[4];
    const int tid = threadIdx.x, lane = tid & 63, wid = tid >> 6;
    const int i = blockIdx.x * 256 + tid;
    const int x = (i < n) ? cnt[i] : 0;
    int v = x;
    #pragma unroll
    for (int off = 1; off < 64; off <<= 1) {
        const int t = __shfl_up(v, off);
        if (lane >= off) v += t;
    }
    if (lane == 63) ws[wid] = v;
    __syncthreads();
    const int w0 = ws[0], w1 = ws[1], w2 = ws[2];
    const int woff = (wid > 0 ? w0 : 0) + (wid > 1 ? w1 : 0) + (wid > 2 ? w2 : 0);
    const int incl = v + woff;
    if (i < n) starts[i] = incl - x;
    if (tid == 255) bsums[blockIdx.x] = incl;
}

__global__ __launch_bounds__(256) void scan_bsums(int* __restrict__ bsums, int nb)
{
    __shared__ int ws[4];
    const int tid = threadIdx.x, lane = tid & 63, wid = tid >> 6;
    const int x = (tid < nb) ? bsums[tid] : 0;
    int v = x;
    #pragma unroll
    for (int off = 1; off < 64; off <<= 1) {
        const int t = __shfl_up(v, off);
        if (lane >= off) v += t;
    }
    if (lane == 63) ws[wid] = v;
    __syncthreads();
    const int w0 = ws[0], w1 = ws[1], w2 = ws[2];
    const int woff = (wid > 0 ? w0 : 0) + (wid > 1 ? w1 : 0) + (wid > 2 ? w2 : 0);
    if (tid < nb) bsums[tid] = (v + woff) - x;
}

__global__ __launch_bounds__(256) void scan_add(
    int* __restrict__ starts, const int* __restrict__ bsums, int n)
{
    const int i = blockIdx.x * 256 + threadIdx.x;
    if (i < n) starts[i] += bsums[blockIdx.x];
}

__global__ __launch_bounds__(256) void bin_place(
    const int* __restrict__ src, const int* __restrict__ dst,
    const float* __restrict__ ew, const int* __restrict__ starts,
    const int* __restrict__ rank, int2* __restrict__ binned, int E)
{
    const int e = blockIdx.x * 256 + threadIdx.x;
    if (e >= E) return;
    const int p = starts[dst[e]] + rank[e];
    binned[p] = make_int2(src[e], __float_as_int(ew[e]));
}

// ---------------------------------------------------------------------------
// Gather-reduce over bf16 n: one wave per dst; lane covers feats {2l, 2l+1}.
// 8-edge unroll. Writes agg as bf16, pre-divided by clamp(sum_w, 1).
// ---------------------------------------------------------------------------
__global__ __launch_bounds__(256) void gather_agg(
    const unsigned short* __restrict__ nsrc, const int2* __restrict__ binned,
    const int* __restrict__ starts, const int* __restrict__ counts,
    unsigned short* __restrict__ agg, int N)
{
    const int lane = threadIdx.x & 63;
    const int d    = blockIdx.x * 4 + (threadIdx.x >> 6);
    if (d >= N) return;
    const int lo = starts[d];
    const int hi = lo + counts[d];
    float accx = 0.f, accy = 0.f, ws = 0.f;
    int p = lo;
    for (; p + 7 < hi; p += 8) {
        int2 s[8];
        unsigned int u[8];
        #pragma unroll
        for (int i = 0; i < 8; i++) s[i] = binned[p + i];
        #pragma unroll
        for (int i = 0; i < 8; i++)
            u[i] = *(const unsigned int*)&nsrc[(size_t)s[i].x * DIM + lane * 2];
        #pragma unroll
        for (int i = 0; i < 8; i++) {
            const float w = __int_as_float(s[i].y);
            accx = fmaf(bflo(u[i]), w, accx);
            accy = fmaf(bfhi(u[i]), w, accy);
            ws += w;
        }
    }
    for (; p < hi; ++p) {
        const int2 sw = binned[p];
        const float w = __int_as_float(sw.y);
        const unsigned int u = *(const unsigned int*)&nsrc[(size_t)sw.x * DIM + lane * 2];
        accx = fmaf(bflo(u), w, accx); accy = fmaf(bfhi(u), w, accy);
        ws += w;
    }
    const float inv = 1.f / fmaxf(ws, 1.f);
    const unsigned int o = ((unsigned int)f2bf(accy * inv) << 16) | f2bf(accx * inv);
    *(unsigned int*)&agg[(size_t)d * DIM + lane * 2] = o;
}

// ---------------------------------------------------------------------------
// MFMA GEMM machinery: 128x128 tile, 4 waves; wave wv owns rows [wv*32,+32).
// All operands bf16 in memory -> staging is pure uint4 copies into swizzled
// LDS: elem (row,k) at [row][(g^(row&7))*8 + k%8], g=k>>3. 0 bank conflicts.
// A/B frag: row|col = lane&15, k = (lane>>4)*8+i. C/D: col=lane&15,
// row=(lane>>4)*4+reg (HW-verified).
// ---------------------------------------------------------------------------

// GEMM1: n = relu(A @ Q^T + qb) -> bf16. K = 128.
__global__ __launch_bounds__(256) void qgemm_relu(
    const unsigned short* __restrict__ A, const unsigned short* __restrict__ Q,
    const float* __restrict__ qb, unsigned short* __restrict__ out, int N)
{
    __shared__ unsigned short Al[128][128];
    __shared__ unsigned short Bl[128][128];
    const int tid = threadIdx.x;
    const int lane = tid & 63, wv = tid >> 6;
    const int lc = lane & 15, lk = lane >> 4;
    const int r0 = blockIdx.x * 128;

    for (int id = tid; id < 2048; id += 256) {
        const int row = id >> 4, g = id & 15;
        const int gs = (g ^ (row & 7)) * 8;
        *(uint4*)&Al[row][gs] = *(const uint4*)&A[(size_t)(r0 + row) * DIM + g * 8];
        *(uint4*)&Bl[row][gs] = *(const uint4*)&Q[(size_t)row * DIM + g * 8];
    }
    __syncthreads();

    f32x4 acc[2][8];
    #pragma unroll
    for (int rf = 0; rf < 2; rf++)
        #pragma unroll
        for (int cf = 0; cf < 8; cf++)
            acc[rf][cf] = (f32x4){0.f, 0.f, 0.f, 0.f};

    #pragma unroll
    for (int ks = 0; ks < 4; ks++) {
        bf16x8 af[2], bfr[8];
        #pragma unroll
        for (int rf = 0; rf < 2; rf++) {
            const int row = wv * 32 + rf * 16 + lc;
            af[rf] = *(const bf16x8*)&Al[row][((ks * 4 + lk) ^ (row & 7)) * 8];
        }
        #pragma unroll
        for (int cf = 0; cf < 8; cf++) {
            const int col = cf * 16 + lc;
            bfr[cf] = *(const bf16x8*)&Bl[col][((ks * 4 + lk) ^ (col & 7)) * 8];
        }
        #pragma unroll
        for (int rf = 0; rf < 2; rf++)
            #pragma unroll
            for (int cf = 0; cf < 8; cf++)
                acc[rf][cf] = __builtin_amdgcn_mfma_f32_16x16x32_bf16(
                    af[rf], bfr[cf], acc[rf][cf], 0, 0, 0);
    }

    float bias[8];
    #pragma unroll
    for (int cf = 0; cf < 8; cf++) bias[cf] = qb[cf * 16 + lc];
    #pragma unroll
    for (int rf = 0; rf < 2; rf++)
        #pragma unroll
        for (int reg = 0; reg < 4; reg++) {
            const int r = r0 + wv * 32 + rf * 16 + lk * 4 + reg;
            if (r >= N) continue;
            #pragma unroll
            for (int cf = 0; cf < 8; cf++)
                out[(size_t)r * DIM + cf * 16 + lc] =
                    f2bf(fmaxf(acc[rf][cf][reg] + bias[cf], 0.f));
        }
}

// GEMM2 + epilogue: z = relu([agg, h] @ W^T + wb); h_next = z/||z||.
// write_out==0: write bf16 into hbuf IN PLACE (each block reads exactly its
// own row range before writing it). write_out==1: write fp32 to out.
__global__ __launch_bounds__(256) void wgemm_norm(
    const unsigned short* __restrict__ agg, unsigned short* __restrict__ hbuf,
    const unsigned short* __restrict__ W, const float* __restrict__ wb,
    float* __restrict__ out, int N, int write_out)
{
    __shared__ unsigned short Al[128][128];
    __shared__ unsigned short Bl[128][128];
    const int tid = threadIdx.x;
    const int lane = tid & 63, wv = tid >> 6;
    const int lc = lane & 15, lk = lane >> 4;
    const int r0 = blockIdx.x * 128;

    f32x4 acc[2][8];
    #pragma unroll
    for (int rf = 0; rf < 2; rf++)
        #pragma unroll
        for (int cf = 0; cf < 8; cf++)
            acc[rf][cf] = (f32x4){0.f, 0.f, 0.f, 0.f};

    for (int part = 0; part < 2; part++) {
        const unsigned short* __restrict__ Ap = part ? hbuf : agg;
        if (part) __syncthreads();  // previous part's LDS reads done
        for (int id = tid; id < 2048; id += 256) {
            const int row = id >> 4, g = id & 15;
            const int gs = (g ^ (row & 7)) * 8;
            *(uint4*)&Al[row][gs] = *(const uint4*)&Ap[(size_t)(r0 + row) * DIM + g * 8];
            *(uint4*)&Bl[row][gs] = *(const uint4*)&W[(size_t)row * 256 + part * 128 + g * 8];
        }
        __syncthreads();

        #pragma unroll
        for (int ks = 0; ks < 4; ks++) {
            bf16x8 af[2], bfr[8];
            #pragma unroll
            for (int rf = 0; rf < 2; rf++) {
                const int row = wv * 32 + rf * 16 + lc;
                af[rf] = *(const bf16x8*)&Al[row][((ks * 4 + lk) ^ (row & 7)) * 8];
            }
            #pragma unroll
            for (int cf = 0; cf < 8; cf++) {
                const int col = cf * 16 + lc;
                bfr[cf] = *(const bf16x8*)&Bl[col][((ks * 4 + lk) ^ (col & 7)) * 8];
            }
            #pragma unroll
            for (int rf = 0; rf < 2; rf++)
                #pragma unroll
                for (int cf = 0; cf < 8; cf++)
                    acc[rf][cf] = __builtin_amdgcn_mfma_f32_16x16x32_bf16(
                        af[rf], bfr[cf], acc[rf][cf], 0, 0, 0);
        }
    }

    float bias[8];
    #pragma unroll
    for (int cf = 0; cf < 8; cf++) bias[cf] = wb[cf * 16 + lc];
    #pragma unroll
    for (int rf = 0; rf < 2; rf++)
        #pragma unroll
        for (int reg = 0; reg < 4; reg++) {
            const int r = r0 + wv * 32 + rf * 16 + lk * 4 + reg;
            float z[8];
            float ss = 0.f;
            #pragma unroll
            for (int cf = 0; cf < 8; cf++) {
                z[cf] = fmaxf(acc[rf][cf][reg] + bias[cf], 0.f);
                ss = fmaf(z[cf], z[cf], ss);
            }
            #pragma unroll
            for (int m = 1; m < 16; m <<= 1) ss += __shfl_xor(ss, m);
            float zn = sqrtf(ss);
            if (zn == 0.f) zn = 1.f;
            const float rn = 1.f / zn;
            if (r < N) {
                if (write_out) {
                    #pragma unroll
                    for (int cf = 0; cf < 8; cf++)
                        out[(size_t)r * DIM + cf * 16 + lc] = z[cf] * rn;
                } else {
                    #pragma unroll
                    for (int cf = 0; cf < 8; cf++)
                        hbuf[(size_t)r * DIM + cf * 16 + lc] = f2bf(z[cf] * rn);
                }
            }
        }
}

extern "C" void kernel_launch(void* const* d_in, const int* in_sizes, int n_in,
                              void* d_out, int out_size, void* d_ws, size_t ws_size,
                              hipStream_t stream) {
    const float* h0  = (const float*)d_in[0];
    const float* ew  = (const float*)d_in[1];
    const float* Qw  = (const float*)d_in[2];
    const float* Qb  = (const float*)d_in[3];
    const float* Ww  = (const float*)d_in[4];
    const float* Wb  = (const float*)d_in[5];
    const int*  esrc = (const int*)d_in[6];
    const int*  edst = (const int*)d_in[7];
    float* out = (float*)d_out;

    unsigned short* hbuf = (unsigned short*)d_ws;            // 12.8 MB
    unsigned short* nbuf = hbuf + (size_t)N_NODES * DIM;     // 12.8 MB
    unsigned short* aggb = nbuf + (size_t)N_NODES * DIM;     // 12.8 MB
    unsigned short* qwb  = aggb + (size_t)N_NODES * DIM;
    unsigned short* wwb  = qwb + 2 * DIM * DIM;
    int*   bins   = (int*)(wwb + 2 * DIM * 2 * DIM);         // counts
    int*   starts = bins + N_NODES;                          // excl scan
    int2*  binned = (int2*)(starts + N_NODES);               // 6.4 MB
    int*   bsums  = (int*)(binned + N_EDGES);
    // rank aliases aggb: fully consumed by bin_place before gather_agg
    // overwrites aggb (stream-ordered), in both layers.
    int*   rank   = (int*)aggb;

    const int gemm_blocks = (N_NODES + 127) / 128;      // 391
    const int edge_blocks = (N_EDGES + 255) / 256;      // 3125
    const int gath_blocks = (N_NODES + 3) / 4;
    const int scan_blocks_n = (N_NODES + 255) / 256;    // 196

    // pre-pass: bf16-ize h0 and weights (rounding identical to old staging)
    cvt_f32_bf16<<<(N_NODES * DIM) / 1024, 256, 0, stream>>>(h0, hbuf, N_NODES * DIM);
    cvt_f32_bf16<<<(2 * DIM * DIM) / 1024, 256, 0, stream>>>(Qw, qwb, 2 * DIM * DIM);
    cvt_f32_bf16<<<(2 * DIM * 2 * DIM) / 1024, 256, 0, stream>>>(Ww, wwb, 2 * DIM * 2 * DIM);

    for (int l = 0; l < 2; l++) {
        const int*   src = esrc + (size_t)l * N_EDGES;
        const int*   dst = edst + (size_t)l * N_EDGES;
        const float* w   = ew + (size_t)l * N_EDGES;

        hipMemsetAsync(bins, 0, N_NODES * sizeof(int), stream);
        hist_rank<<<edge_blocks, 256, 0, stream>>>(dst, bins, rank, N_EDGES);
        scan_blocks<<<scan_blocks_n, 256, 0, stream>>>(bins, starts, bsums, N_NODES);
        scan_bsums<<<1, 256, 0, stream>>>(bsums, scan_blocks_n);
        scan_add<<<scan_blocks_n, 256, 0, stream>>>(starts, bsums, N_NODES);
        bin_place<<<edge_blocks, 256, 0, stream>>>(src, dst, w, starts, rank, binned, N_EDGES);
        qgemm_relu<<<gemm_blocks, 256, 0, stream>>>(
            hbuf, qwb + (size_t)l * DIM * DIM, Qb + (size_t)l * DIM, nbuf, N_NODES);
        gather_agg<<<gath_blocks, 256, 0, stream>>>(nbuf, binned, starts, bins, aggb, N_NODES);
        wgemm_norm<<<gemm_blocks, 256, 0, stream>>>(
            aggb, hbuf, wwb + (size_t)l * DIM * 2 * DIM, Wb + (size_t)l * DIM,
            out, N_NODES, l == 1 ? 1 : 0);
    }
}